// Round 12
// baseline (1728.471 us; speedup 1.0000x reference)
//
#include <hip/hip_runtime.h>

typedef __attribute__((ext_vector_type(4))) float f32x4;
typedef __attribute__((ext_vector_type(8))) __bf16 bf16x8;
typedef __attribute__((ext_vector_type(8))) unsigned short u16x8;

#define DI __device__ __forceinline__

constexpr int S_LEN = 4096;
constexpr int NBATCH = 4;
constexpr int HD = 1024;
constexpr int MROWS = NBATCH * S_LEN;  // 16384
constexpr int NCHUNK = 256;
constexpr int CHUNKL = 16;

DI float bf2f(unsigned short u) {
  unsigned int x = ((unsigned int)u) << 16;
  return __builtin_bit_cast(float, x);
}
DI unsigned short f2bf(float f) {
  unsigned int u = __builtin_bit_cast(unsigned int, f);
  u += 0x7FFFu + ((u >> 16) & 1u);  // RNE; inputs finite
  return (unsigned short)(u >> 16);
}
DI float sigmoid_f(float x) { return 1.0f / (1.0f + expf(-x)); }
DI float gelu_f(float x) {
  float u = 0.7978845608028654f * (x + 0.044715f * x * x * x);
  return 0.5f * x * (1.0f + tanhf(u));
}
DI void gload16(const void* g, void* l) {
  __builtin_amdgcn_global_load_lds(
      (const __attribute__((address_space(1))) unsigned int*)g,
      (__attribute__((address_space(3))) unsigned int*)l, 16, 0, 0);
}

// ---------------- weight transpose+convert: dst[n][k] = bf16(src[k][n]) ----
struct TDesc {
  const float* src;       // [1024][1024] row-major
  unsigned short* dst;    // bf16 bits
  int ldDst;
  int rowOff;
  int colOff;
};
struct TArgs { TDesc d[9]; };

__global__ __launch_bounds__(256) void transpose_pack(TArgs args) {
  const int w = blockIdx.x >> 8;
  const int tile = blockIdx.x & 255;
  TDesc dd = args.d[w];
  const int tn = (tile & 15) * 64;
  const int tk = (tile >> 4) * 64;
  __shared__ float t[64][65];
  const int tx = threadIdx.x & 63, ty = threadIdx.x >> 6;
#pragma unroll
  for (int r = 0; r < 16; ++r) {
    int kk = ty * 16 + r;
    t[kk][tx] = dd.src[(size_t)(tk + kk) * 1024 + tn + tx];
  }
  __syncthreads();
#pragma unroll
  for (int r = 0; r < 16; ++r) {
    int nn = ty * 16 + r;
    dd.dst[(size_t)(dd.rowOff + tn + nn) * dd.ldDst + dd.colOff + tk + tx] =
        f2bf(t[tx][nn]);
  }
}

// ---------------- bias packing ----------------
__global__ __launch_bounds__(256) void bias_pack(
    const float* bxf, const float* bxb, const float* bgxf, const float* bgaf,
    const float* bgxb, const float* bgab, const float* bof, const float* bob,
    float* b1, float* bgf, float* bgb, float* bos) {
  int i = blockIdx.x * 256 + threadIdx.x;
  if (i < 1024) {
    b1[i] = bxf[i];
    bgf[i] = bgxf[i];
    bgb[i] = bgxb[i];
    bos[i] = bof[i] + bob[i];
  } else if (i < 2048) {
    int j = i - 1024;
    b1[i] = bxb[j];
    bgf[i] = bgaf[j];
    bgb[i] = bgab[j];
  }
}

// ---------------- gelu(x) -> bf16 ----------------
__global__ __launch_bounds__(256) void gelu_in(const float4* __restrict__ x,
                                               ushort4* __restrict__ xg) {
  int i = blockIdx.x * 256 + threadIdx.x;
  float4 v = x[i];
  ushort4 o;
  o.x = f2bf(gelu_f(v.x));
  o.y = f2bf(gelu_f(v.y));
  o.z = f2bf(gelu_f(v.z));
  o.w = f2bf(gelu_f(v.w));
  xg[i] = o;
}

// ---------------- GEMM: C = A[M x K] * BT[N x K]^T, fused epilogues --------
// BM=256 x BN=128 block, BK=64 single-buffer (48 KB LDS), 512 threads
// (8 waves, 4M x 2N, wave tile 64x64 = R10's per-wave profile). 3 blocks/CU
// by LDS -> 24 waves (75% potential occupancy); 1 vmcnt(0) drain per K64 per
// 2x output area. R&7 XOR slot swizzle both-sides; XCD-chunked block map.
enum { EPI_BF16 = 0, EPI_X2 = 2, EPI_FINAL = 3 };

template <int EPI>
__global__ __launch_bounds__(512, 6) void gemm_bt(
    const unsigned short* __restrict__ A, int lda,
    const unsigned short* __restrict__ BT, int K, int nbx,
    const float* __restrict__ bias, const float* __restrict__ aux,
    float* __restrict__ fout, unsigned short* __restrict__ bout, int ldo) {
  constexpr int BK = 64;
  __shared__ __align__(16) unsigned short lA[256 * BK];  // 32 KB
  __shared__ __align__(16) unsigned short lB[128 * BK];  // 16 KB
  const int t = threadIdx.x;
  const int lane = t & 63, wave = t >> 6;
  const int nwg = gridDim.x;  // multiple of 8
  int wg = blockIdx.x;
  wg = (wg & 7) * (nwg >> 3) + (wg >> 3);  // XCD-chunked, bijective
  const int by = wg / nbx, bx = wg - by * nbx;
  const int m0 = by * 256, n0 = bx * 128;
  const int wm = (wave >> 1) * 64, wn = (wave & 1) * 64;  // 4M x 2N
  f32x4 acc[4][4] = {};
  // staging: thread t, pass j -> row R = (t>>3) + j*64, linear slot sl = t&7.
  // Global source slot pre-swizzled: sg = sl ^ (R&7); (R&7) invariant in j.
  const int Rs = t >> 3;  // 0..63
  const int sg = (t & 7) ^ (Rs & 7);
  const unsigned short* Ag = A + (size_t)(m0 + Rs) * lda + sg * 8;
  const unsigned short* Bg = BT + (size_t)(n0 + Rs) * K + sg * 8;
  const int r = lane & 15, g = lane >> 4;
  const int nK = K / BK;

  for (int kt = 0; kt < nK; ++kt) {
    __syncthreads();  // WAR: all waves done reading previous tile
    {
      const unsigned short* a0 = Ag + kt * BK;
      const unsigned short* b0 = Bg + kt * BK;
      unsigned short* lAp = lA + t * 8;
      unsigned short* lBp = lB + t * 8;
#pragma unroll
      for (int j = 0; j < 4; ++j)
        gload16(a0 + (size_t)(j * 64) * lda, lAp + j * 4096);
#pragma unroll
      for (int j = 0; j < 2; ++j)
        gload16(b0 + (size_t)(j * 64) * K, lBp + j * 4096);
    }
    __syncthreads();  // RAW: staged tile visible (vmcnt0 drain)
#pragma unroll
    for (int ks = 0; ks < 2; ++ks) {
      bf16x8 af[4], bv[4];
#pragma unroll
      for (int i = 0; i < 4; ++i) {
        const int R = wm + i * 16 + r;
        af[i] = __builtin_bit_cast(
            bf16x8,
            *(const u16x8*)&lA[R * BK + ((ks * 4 + g) ^ (R & 7)) * 8]);
      }
#pragma unroll
      for (int j = 0; j < 4; ++j) {
        const int R = wn + j * 16 + r;
        bv[j] = __builtin_bit_cast(
            bf16x8,
            *(const u16x8*)&lB[R * BK + ((ks * 4 + g) ^ (R & 7)) * 8]);
      }
#pragma unroll
      for (int i = 0; i < 4; ++i)
#pragma unroll
        for (int j = 0; j < 4; ++j)
          acc[i][j] = __builtin_amdgcn_mfma_f32_16x16x32_bf16(
              af[i], bv[j], acc[i][j], 0, 0, 0);
    }
  }

  const int g4 = g * 4;
#pragma unroll
  for (int i = 0; i < 4; ++i) {
#pragma unroll
    for (int j = 0; j < 4; ++j) {
      const int col = n0 + wn + j * 16 + r;
      const float bc = bias[col];
#pragma unroll
      for (int q = 0; q < 4; ++q) {
        const int row = m0 + wm + i * 16 + g4 + q;
        const size_t o = (size_t)row * ldo + col;
        float v = acc[i][j][q] + bc;
        if constexpr (EPI == EPI_BF16) {
          bout[o] = f2bf(v);
        } else if constexpr (EPI == EPI_X2) {
          float x2 = 0.5f * v + aux[o];  // (fwd+bwd)/2 + identity
          bout[o] = f2bf(gelu_f(x2));
        } else {  // EPI_FINAL
          fout[o] = v + aux[o];
        }
      }
    }
  }
}

// ---------------- chunked linear scan h_t = a*h + xin ----------------------
template <int REV>
__global__ __launch_bounds__(256) void scan_p1(
    const unsigned short* __restrict__ gates,
    const unsigned short* __restrict__ x1,
    const float* __restrict__ a_logit, float* __restrict__ Pf,
    float* __restrict__ Ee) {
  const int c0 = threadIdx.x * 4;
  const int chunk = blockIdx.y, b = blockIdx.z;
  float ae[4], h[4] = {0.f, 0.f, 0.f, 0.f}, P[4] = {1.f, 1.f, 1.f, 1.f};
#pragma unroll
  for (int k = 0; k < 4; ++k) ae[k] = sigmoid_f(a_logit[c0 + k]);
  for (int i = 0; i < CHUNKL; ++i) {
    const int p = chunk * CHUNKL + i;
    const int s = REV ? (S_LEN - 1 - p) : p;
    const size_t row = (size_t)b * S_LEN + s;
    const ushort4 gxv = *(const ushort4*)&gates[row * 2048 + c0];
    const ushort4 gav = *(const ushort4*)&gates[row * 2048 + 1024 + c0];
    const ushort4 xvv = *(const ushort4*)&x1[row * 2048 + c0];
    const unsigned short* gxp = (const unsigned short*)&gxv;
    const unsigned short* gap = (const unsigned short*)&gav;
    const unsigned short* xvp = (const unsigned short*)&xvv;
#pragma unroll
    for (int k = 0; k < 4; ++k) {
      const float gx = sigmoid_f(bf2f(gxp[k]));
      const float ga = sigmoid_f(bf2f(gap[k]));
      const float a = ga * ae[k];
      const float xin = sqrtf(fmaxf(0.f, 1.f - a * a)) * (gx * bf2f(xvp[k]));
      h[k] = fmaf(a, h[k], xin);
      P[k] *= a;
    }
  }
  const size_t idx = ((size_t)b * NCHUNK + chunk) * HD + c0;
#pragma unroll
  for (int k = 0; k < 4; ++k) {
    Pf[idx + k] = P[k];
    Ee[idx + k] = h[k];
  }
}

__global__ __launch_bounds__(256) void scan_p2(const float* __restrict__ Pf,
                                               const float* __restrict__ Ee,
                                               float* __restrict__ Ci) {
  const int c0 = threadIdx.x * 4;
  const int b = blockIdx.y;
  float4 carry = {0.f, 0.f, 0.f, 0.f};
  for (int j = 0; j < NCHUNK; ++j) {
    const size_t idx = ((size_t)b * NCHUNK + j) * HD + c0;
    *(float4*)&Ci[idx] = carry;
    const float4 Pv = *(const float4*)&Pf[idx];
    const float4 Ev = *(const float4*)&Ee[idx];
    carry.x = Ev.x + Pv.x * carry.x;
    carry.y = Ev.y + Pv.y * carry.y;
    carry.z = Ev.z + Pv.z * carry.z;
    carry.w = Ev.w + Pv.w * carry.w;
  }
}

template <int REV>
__global__ __launch_bounds__(256) void scan_p3(
    const unsigned short* __restrict__ gates,
    const unsigned short* __restrict__ x1,
    const float* __restrict__ a_logit, const float* __restrict__ Ci,
    unsigned short* __restrict__ hout) {
  const int c0 = threadIdx.x * 4;
  const int chunk = blockIdx.y, b = blockIdx.z;
  float ae[4], h[4];
#pragma unroll
  for (int k = 0; k < 4; ++k) {
    ae[k] = sigmoid_f(a_logit[c0 + k]);
    h[k] = Ci[((size_t)b * NCHUNK + chunk) * HD + c0 + k];
  }
  for (int i = 0; i < CHUNKL; ++i) {
    const int p = chunk * CHUNKL + i;
    const int s = REV ? (S_LEN - 1 - p) : p;
    const size_t row = (size_t)b * S_LEN + s;
    const ushort4 gxv = *(const ushort4*)&gates[row * 2048 + c0];
    const ushort4 gav = *(const ushort4*)&gates[row * 2048 + 1024 + c0];
    const ushort4 xvv = *(const ushort4*)&x1[row * 2048 + c0];
    const unsigned short* gxp = (const unsigned short*)&gxv;
    const unsigned short* gap = (const unsigned short*)&gav;
    const unsigned short* xvp = (const unsigned short*)&xvv;
    ushort4 ho;
    unsigned short* hop = (unsigned short*)&ho;
#pragma unroll
    for (int k = 0; k < 4; ++k) {
      const float gx = sigmoid_f(bf2f(gxp[k]));
      const float ga = sigmoid_f(bf2f(gap[k]));
      const float a = ga * ae[k];
      const float xin = sqrtf(fmaxf(0.f, 1.f - a * a)) * (gx * bf2f(xvp[k]));
      h[k] = fmaf(a, h[k], xin);
      hop[k] = f2bf(h[k]);
    }
    *(ushort4*)&hout[row * 2048 + c0] = ho;
  }
}

// ---------------- launcher ----------------
extern "C" void kernel_launch(void* const* d_in, const int* in_sizes, int n_in,
                              void* d_out, int out_size, void* d_ws,
                              size_t ws_size, hipStream_t stream) {
  const float* x = (const float*)d_in[0];
  const float* f_alog = (const float*)d_in[1];
  const float* f_Wx = (const float*)d_in[2];
  const float* f_bx = (const float*)d_in[3];
  const float* f_Wgx = (const float*)d_in[4];
  const float* f_bgx = (const float*)d_in[5];
  const float* f_Wga = (const float*)d_in[6];
  const float* f_bga = (const float*)d_in[7];
  const float* f_Wo = (const float*)d_in[8];
  const float* f_bo = (const float*)d_in[9];
  const float* b_alog = (const float*)d_in[10];
  const float* b_Wx = (const float*)d_in[11];
  const float* b_bx = (const float*)d_in[12];
  const float* b_Wgx = (const float*)d_in[13];
  const float* b_bgx = (const float*)d_in[14];
  const float* b_Wga = (const float*)d_in[15];
  const float* b_bga = (const float*)d_in[16];
  const float* b_Wo = (const float*)d_in[17];
  const float* b_bo = (const float*)d_in[18];
  const float* ld_W = (const float*)d_in[19];
  const float* ld_b = (const float*)d_in[20];
  float* out = (float*)d_out;
  (void)in_sizes; (void)n_in; (void)out_size;

  const size_t MB = 1ull << 20;
  if (ws_size < 159 * MB) return;  // fail clean, not fault

  char* ws = (char*)d_ws;
  unsigned short* B1T = (unsigned short*)(ws + 0 * MB);    // [2048][1024]
  unsigned short* B2Tf = (unsigned short*)(ws + 4 * MB);   // [2048][1024]
  unsigned short* B2Tb = (unsigned short*)(ws + 8 * MB);   // [2048][1024]
  unsigned short* B3T = (unsigned short*)(ws + 12 * MB);   // [1024][2048]
  unsigned short* B4T = (unsigned short*)(ws + 16 * MB);   // [1024][1024]
  float* b1 = (float*)(ws + 18 * MB);
  float* bgf = (float*)(ws + 18 * MB + 8192);
  float* bgb = (float*)(ws + 18 * MB + 16384);
  float* bos = (float*)(ws + 18 * MB + 24576);
  unsigned short* x1b = (unsigned short*)(ws + 19 * MB);   // [16384][2048] bf16
  // region C (64 MB), time-shared: xg -> gates -> g2
  unsigned short* xg = (unsigned short*)(ws + 83 * MB);    // [16384][1024] bf16
  unsigned short* gates = (unsigned short*)(ws + 83 * MB); // [16384][2048] bf16
  unsigned short* g2 = (unsigned short*)(ws + 83 * MB);    // [16384][1024] bf16
  float* Pf = (float*)(ws + 147 * MB);                     // 4 MB
  float* Ee = (float*)(ws + 151 * MB);                     // 4 MB
  float* Ci = (float*)(ws + 155 * MB);                     // 4 MB
  unsigned short* hcat = (unsigned short*)d_out;           // [16384][2048] bf16

  TArgs ta;
  ta.d[0] = {f_Wx, B1T, 1024, 0, 0};
  ta.d[1] = {b_Wx, B1T, 1024, 1024, 0};
  ta.d[2] = {f_Wgx, B2Tf, 1024, 0, 0};
  ta.d[3] = {f_Wga, B2Tf, 1024, 1024, 0};
  ta.d[4] = {b_Wgx, B2Tb, 1024, 0, 0};
  ta.d[5] = {b_Wga, B2Tb, 1024, 1024, 0};
  ta.d[6] = {f_Wo, B3T, 2048, 0, 0};
  ta.d[7] = {b_Wo, B3T, 2048, 0, 1024};
  ta.d[8] = {ld_W, B4T, 1024, 0, 0};

  transpose_pack<<<dim3(9 * 256), dim3(256), 0, stream>>>(ta);
  bias_pack<<<dim3(8), dim3(256), 0, stream>>>(f_bx, b_bx, f_bgx, f_bga, b_bgx,
                                               b_bga, f_bo, b_bo, b1, bgf, bgb,
                                               bos);
  gelu_in<<<dim3(MROWS * HD / 4 / 256), dim3(256), 0, stream>>>(
      (const float4*)x, (ushort4*)xg);

  // G1: x1 = gelu(x) @ [Wx_f | Wx_b] + [bx_f | bx_b]   -> bf16 [16384][2048]
  gemm_bt<EPI_BF16><<<dim3(1024), dim3(512), 0, stream>>>(
      xg, 1024, B1T, 1024, 16, b1, nullptr, nullptr, x1b, 2048);

  // fwd: gate pre-acts (bf16), then 3-phase scan -> hcat[:, 0:1024]
  gemm_bt<EPI_BF16><<<dim3(1024), dim3(512), 0, stream>>>(
      x1b, 2048, B2Tf, 1024, 16, bgf, nullptr, nullptr, gates, 2048);
  scan_p1<0><<<dim3(1, NCHUNK, NBATCH), dim3(256), 0, stream>>>(gates, x1b,
                                                                f_alog, Pf, Ee);
  scan_p2<<<dim3(1, NBATCH), dim3(256), 0, stream>>>(Pf, Ee, Ci);
  scan_p3<0><<<dim3(1, NCHUNK, NBATCH), dim3(256), 0, stream>>>(
      gates, x1b, f_alog, Ci, hcat);

  // bwd: gate pre-acts (reusing gates), reverse scan -> hcat[:, 1024:2048]
  gemm_bt<EPI_BF16><<<dim3(1024), dim3(512), 0, stream>>>(
      x1b + 1024, 2048, B2Tb, 1024, 16, bgb, nullptr, nullptr, gates, 2048);
  scan_p1<1><<<dim3(1, NCHUNK, NBATCH), dim3(256), 0, stream>>>(
      gates, x1b + 1024, b_alog, Pf, Ee);
  scan_p2<<<dim3(1, NBATCH), dim3(256), 0, stream>>>(Pf, Ee, Ci);
  scan_p3<1><<<dim3(1, NCHUNK, NBATCH), dim3(256), 0, stream>>>(
      gates, x1b + 1024, b_alog, Ci, hcat + 1024);

  // G3: g2 = gelu( ([h_f|h_b] @ [Wo_f;Wo_b] + bo_f+bo_b)/2 + x )
  gemm_bt<EPI_X2><<<dim3(512), dim3(512), 0, stream>>>(
      hcat, 2048, B3T, 2048, 8, bos, x, nullptr, g2, 1024);

  // G4: out = g2 @ ld_W + ld_b + x
  gemm_bt<EPI_FINAL><<<dim3(512), dim3(512), 0, stream>>>(
      g2, 1024, B4T, 1024, 8, ld_b, x, out, nullptr, 1024);
}

// Round 13
// 641.859 us; speedup vs baseline: 2.6929x; 2.6929x over previous
//
#include <hip/hip_runtime.h>

typedef __attribute__((ext_vector_type(4))) float f32x4;
typedef __attribute__((ext_vector_type(8))) __bf16 bf16x8;
typedef __attribute__((ext_vector_type(8))) unsigned short u16x8;

#define DI __device__ __forceinline__

constexpr int S_LEN = 4096;
constexpr int NBATCH = 4;
constexpr int HD = 1024;
constexpr int MROWS = NBATCH * S_LEN;  // 16384
constexpr int NCHUNK = 256;
constexpr int CHUNKL = 16;

DI float bf2f(unsigned short u) {
  unsigned int x = ((unsigned int)u) << 16;
  return __builtin_bit_cast(float, x);
}
DI unsigned short f2bf(float f) {
  unsigned int u = __builtin_bit_cast(unsigned int, f);
  u += 0x7FFFu + ((u >> 16) & 1u);  // RNE; inputs finite
  return (unsigned short)(u >> 16);
}
DI float sigmoid_f(float x) { return 1.0f / (1.0f + expf(-x)); }
DI float gelu_f(float x) {
  float u = 0.7978845608028654f * (x + 0.044715f * x * x * x);
  return 0.5f * x * (1.0f + tanhf(u));
}
DI void gload16(const void* g, void* l) {
  __builtin_amdgcn_global_load_lds(
      (const __attribute__((address_space(1))) unsigned int*)g,
      (__attribute__((address_space(3))) unsigned int*)l, 16, 0, 0);
}

// ---------------- weight transpose+convert: dst[n][k] = bf16(src[k][n]) ----
struct TDesc {
  const float* src;       // [1024][1024] row-major
  unsigned short* dst;    // bf16 bits
  int ldDst;
  int rowOff;
  int colOff;
};
struct TArgs { TDesc d[9]; };

__global__ __launch_bounds__(256) void transpose_pack(TArgs args) {
  const int w = blockIdx.x >> 8;
  const int tile = blockIdx.x & 255;
  TDesc dd = args.d[w];
  const int tn = (tile & 15) * 64;
  const int tk = (tile >> 4) * 64;
  __shared__ float t[64][65];
  const int tx = threadIdx.x & 63, ty = threadIdx.x >> 6;
#pragma unroll
  for (int r = 0; r < 16; ++r) {
    int kk = ty * 16 + r;
    t[kk][tx] = dd.src[(size_t)(tk + kk) * 1024 + tn + tx];
  }
  __syncthreads();
#pragma unroll
  for (int r = 0; r < 16; ++r) {
    int nn = ty * 16 + r;
    dd.dst[(size_t)(dd.rowOff + tn + nn) * dd.ldDst + dd.colOff + tk + tx] =
        f2bf(t[tx][nn]);
  }
}

// ---------------- bias packing ----------------
__global__ __launch_bounds__(256) void bias_pack(
    const float* bxf, const float* bxb, const float* bgxf, const float* bgaf,
    const float* bgxb, const float* bgab, const float* bof, const float* bob,
    float* b1, float* bgf, float* bgb, float* bos) {
  int i = blockIdx.x * 256 + threadIdx.x;
  if (i < 1024) {
    b1[i] = bxf[i];
    bgf[i] = bgxf[i];
    bgb[i] = bgxb[i];
    bos[i] = bof[i] + bob[i];
  } else if (i < 2048) {
    int j = i - 1024;
    b1[i] = bxb[j];
    bgf[i] = bgaf[j];
    bgb[i] = bgab[j];
  }
}

// ---------------- gelu(x) -> bf16 ----------------
__global__ __launch_bounds__(256) void gelu_in(const float4* __restrict__ x,
                                               ushort4* __restrict__ xg) {
  int i = blockIdx.x * 256 + threadIdx.x;
  float4 v = x[i];
  ushort4 o;
  o.x = f2bf(gelu_f(v.x));
  o.y = f2bf(gelu_f(v.y));
  o.z = f2bf(gelu_f(v.z));
  o.w = f2bf(gelu_f(v.w));
  xg[i] = o;
}

// ---------------- GEMM: C = A[M x K] * BT[N x K]^T, fused epilogues --------
// BM=256 x BN=128 block, BK=64 single-buffer (48 KB LDS), 512 threads
// (8 waves, 4M x 2N, wave tile 64x64 = R10's per-wave profile).
// __launch_bounds__(512,4): VGPR cap 128 -- no spills (R12's (512,6) cap of
// 85 spilled acc to scratch: WRITE_SIZE 57->624 MB, MfmaUtil 8%).
// 2 blocks/CU by VGPR -> 16 waves (50%); 1 vmcnt(0) drain per K64 per 2x
// output area vs R10. R&7 XOR slot swizzle both-sides; XCD-chunked map.
enum { EPI_BF16 = 0, EPI_X2 = 2, EPI_FINAL = 3 };

template <int EPI>
__global__ __launch_bounds__(512, 4) void gemm_bt(
    const unsigned short* __restrict__ A, int lda,
    const unsigned short* __restrict__ BT, int K, int nbx,
    const float* __restrict__ bias, const float* __restrict__ aux,
    float* __restrict__ fout, unsigned short* __restrict__ bout, int ldo) {
  constexpr int BK = 64;
  __shared__ __align__(16) unsigned short lA[256 * BK];  // 32 KB
  __shared__ __align__(16) unsigned short lB[128 * BK];  // 16 KB
  const int t = threadIdx.x;
  const int lane = t & 63, wave = t >> 6;
  const int nwg = gridDim.x;  // multiple of 8
  int wg = blockIdx.x;
  wg = (wg & 7) * (nwg >> 3) + (wg >> 3);  // XCD-chunked, bijective
  const int by = wg / nbx, bx = wg - by * nbx;
  const int m0 = by * 256, n0 = bx * 128;
  const int wm = (wave >> 1) * 64, wn = (wave & 1) * 64;  // 4M x 2N
  f32x4 acc[4][4] = {};
  // staging: thread t, pass j -> row R = (t>>3) + j*64, linear slot sl = t&7.
  // Global source slot pre-swizzled: sg = sl ^ (R&7); (R&7) invariant in j.
  const int Rs = t >> 3;  // 0..63
  const int sg = (t & 7) ^ (Rs & 7);
  const unsigned short* Ag = A + (size_t)(m0 + Rs) * lda + sg * 8;
  const unsigned short* Bg = BT + (size_t)(n0 + Rs) * K + sg * 8;
  const int r = lane & 15, g = lane >> 4;
  const int nK = K / BK;

  for (int kt = 0; kt < nK; ++kt) {
    __syncthreads();  // WAR: all waves done reading previous tile
    {
      const unsigned short* a0 = Ag + kt * BK;
      const unsigned short* b0 = Bg + kt * BK;
      unsigned short* lAp = lA + t * 8;
      unsigned short* lBp = lB + t * 8;
#pragma unroll
      for (int j = 0; j < 4; ++j)
        gload16(a0 + (size_t)(j * 64) * lda, lAp + j * 4096);
#pragma unroll
      for (int j = 0; j < 2; ++j)
        gload16(b0 + (size_t)(j * 64) * K, lBp + j * 4096);
    }
    __syncthreads();  // RAW: staged tile visible (vmcnt0 drain)
#pragma unroll
    for (int ks = 0; ks < 2; ++ks) {
      bf16x8 af[4], bv[4];
#pragma unroll
      for (int i = 0; i < 4; ++i) {
        const int R = wm + i * 16 + r;
        af[i] = __builtin_bit_cast(
            bf16x8,
            *(const u16x8*)&lA[R * BK + ((ks * 4 + g) ^ (R & 7)) * 8]);
      }
#pragma unroll
      for (int j = 0; j < 4; ++j) {
        const int R = wn + j * 16 + r;
        bv[j] = __builtin_bit_cast(
            bf16x8,
            *(const u16x8*)&lB[R * BK + ((ks * 4 + g) ^ (R & 7)) * 8]);
      }
#pragma unroll
      for (int i = 0; i < 4; ++i)
#pragma unroll
        for (int j = 0; j < 4; ++j)
          acc[i][j] = __builtin_amdgcn_mfma_f32_16x16x32_bf16(
              af[i], bv[j], acc[i][j], 0, 0, 0);
    }
  }

  const int g4 = g * 4;
#pragma unroll
  for (int i = 0; i < 4; ++i) {
#pragma unroll
    for (int j = 0; j < 4; ++j) {
      const int col = n0 + wn + j * 16 + r;
      const float bc = bias[col];
#pragma unroll
      for (int q = 0; q < 4; ++q) {
        const int row = m0 + wm + i * 16 + g4 + q;
        const size_t o = (size_t)row * ldo + col;
        float v = acc[i][j][q] + bc;
        if constexpr (EPI == EPI_BF16) {
          bout[o] = f2bf(v);
        } else if constexpr (EPI == EPI_X2) {
          float x2 = 0.5f * v + aux[o];  // (fwd+bwd)/2 + identity
          bout[o] = f2bf(gelu_f(x2));
        } else {  // EPI_FINAL
          fout[o] = v + aux[o];
        }
      }
    }
  }
}

// ---------------- chunked linear scan h_t = a*h + xin ----------------------
template <int REV>
__global__ __launch_bounds__(256) void scan_p1(
    const unsigned short* __restrict__ gates,
    const unsigned short* __restrict__ x1,
    const float* __restrict__ a_logit, float* __restrict__ Pf,
    float* __restrict__ Ee) {
  const int c0 = threadIdx.x * 4;
  const int chunk = blockIdx.y, b = blockIdx.z;
  float ae[4], h[4] = {0.f, 0.f, 0.f, 0.f}, P[4] = {1.f, 1.f, 1.f, 1.f};
#pragma unroll
  for (int k = 0; k < 4; ++k) ae[k] = sigmoid_f(a_logit[c0 + k]);
  for (int i = 0; i < CHUNKL; ++i) {
    const int p = chunk * CHUNKL + i;
    const int s = REV ? (S_LEN - 1 - p) : p;
    const size_t row = (size_t)b * S_LEN + s;
    const ushort4 gxv = *(const ushort4*)&gates[row * 2048 + c0];
    const ushort4 gav = *(const ushort4*)&gates[row * 2048 + 1024 + c0];
    const ushort4 xvv = *(const ushort4*)&x1[row * 2048 + c0];
    const unsigned short* gxp = (const unsigned short*)&gxv;
    const unsigned short* gap = (const unsigned short*)&gav;
    const unsigned short* xvp = (const unsigned short*)&xvv;
#pragma unroll
    for (int k = 0; k < 4; ++k) {
      const float gx = sigmoid_f(bf2f(gxp[k]));
      const float ga = sigmoid_f(bf2f(gap[k]));
      const float a = ga * ae[k];
      const float xin = sqrtf(fmaxf(0.f, 1.f - a * a)) * (gx * bf2f(xvp[k]));
      h[k] = fmaf(a, h[k], xin);
      P[k] *= a;
    }
  }
  const size_t idx = ((size_t)b * NCHUNK + chunk) * HD + c0;
#pragma unroll
  for (int k = 0; k < 4; ++k) {
    Pf[idx + k] = P[k];
    Ee[idx + k] = h[k];
  }
}

__global__ __launch_bounds__(256) void scan_p2(const float* __restrict__ Pf,
                                               const float* __restrict__ Ee,
                                               float* __restrict__ Ci) {
  const int c0 = threadIdx.x * 4;
  const int b = blockIdx.y;
  float4 carry = {0.f, 0.f, 0.f, 0.f};
  for (int j = 0; j < NCHUNK; ++j) {
    const size_t idx = ((size_t)b * NCHUNK + j) * HD + c0;
    *(float4*)&Ci[idx] = carry;
    const float4 Pv = *(const float4*)&Pf[idx];
    const float4 Ev = *(const float4*)&Ee[idx];
    carry.x = Ev.x + Pv.x * carry.x;
    carry.y = Ev.y + Pv.y * carry.y;
    carry.z = Ev.z + Pv.z * carry.z;
    carry.w = Ev.w + Pv.w * carry.w;
  }
}

template <int REV>
__global__ __launch_bounds__(256) void scan_p3(
    const unsigned short* __restrict__ gates,
    const unsigned short* __restrict__ x1,
    const float* __restrict__ a_logit, const float* __restrict__ Ci,
    unsigned short* __restrict__ hout) {
  const int c0 = threadIdx.x * 4;
  const int chunk = blockIdx.y, b = blockIdx.z;
  float ae[4], h[4];
#pragma unroll
  for (int k = 0; k < 4; ++k) {
    ae[k] = sigmoid_f(a_logit[c0 + k]);
    h[k] = Ci[((size_t)b * NCHUNK + chunk) * HD + c0 + k];
  }
  for (int i = 0; i < CHUNKL; ++i) {
    const int p = chunk * CHUNKL + i;
    const int s = REV ? (S_LEN - 1 - p) : p;
    const size_t row = (size_t)b * S_LEN + s;
    const ushort4 gxv = *(const ushort4*)&gates[row * 2048 + c0];
    const ushort4 gav = *(const ushort4*)&gates[row * 2048 + 1024 + c0];
    const ushort4 xvv = *(const ushort4*)&x1[row * 2048 + c0];
    const unsigned short* gxp = (const unsigned short*)&gxv;
    const unsigned short* gap = (const unsigned short*)&gav;
    const unsigned short* xvp = (const unsigned short*)&xvv;
    ushort4 ho;
    unsigned short* hop = (unsigned short*)&ho;
#pragma unroll
    for (int k = 0; k < 4; ++k) {
      const float gx = sigmoid_f(bf2f(gxp[k]));
      const float ga = sigmoid_f(bf2f(gap[k]));
      const float a = ga * ae[k];
      const float xin = sqrtf(fmaxf(0.f, 1.f - a * a)) * (gx * bf2f(xvp[k]));
      h[k] = fmaf(a, h[k], xin);
      hop[k] = f2bf(h[k]);
    }
    *(ushort4*)&hout[row * 2048 + c0] = ho;
  }
}

// ---------------- launcher ----------------
extern "C" void kernel_launch(void* const* d_in, const int* in_sizes, int n_in,
                              void* d_out, int out_size, void* d_ws,
                              size_t ws_size, hipStream_t stream) {
  const float* x = (const float*)d_in[0];
  const float* f_alog = (const float*)d_in[1];
  const float* f_Wx = (const float*)d_in[2];
  const float* f_bx = (const float*)d_in[3];
  const float* f_Wgx = (const float*)d_in[4];
  const float* f_bgx = (const float*)d_in[5];
  const float* f_Wga = (const float*)d_in[6];
  const float* f_bga = (const float*)d_in[7];
  const float* f_Wo = (const float*)d_in[8];
  const float* f_bo = (const float*)d_in[9];
  const float* b_alog = (const float*)d_in[10];
  const float* b_Wx = (const float*)d_in[11];
  const float* b_bx = (const float*)d_in[12];
  const float* b_Wgx = (const float*)d_in[13];
  const float* b_bgx = (const float*)d_in[14];
  const float* b_Wga = (const float*)d_in[15];
  const float* b_bga = (const float*)d_in[16];
  const float* b_Wo = (const float*)d_in[17];
  const float* b_bo = (const float*)d_in[18];
  const float* ld_W = (const float*)d_in[19];
  const float* ld_b = (const float*)d_in[20];
  float* out = (float*)d_out;
  (void)in_sizes; (void)n_in; (void)out_size;

  const size_t MB = 1ull << 20;
  if (ws_size < 159 * MB) return;  // fail clean, not fault

  char* ws = (char*)d_ws;
  unsigned short* B1T = (unsigned short*)(ws + 0 * MB);    // [2048][1024]
  unsigned short* B2Tf = (unsigned short*)(ws + 4 * MB);   // [2048][1024]
  unsigned short* B2Tb = (unsigned short*)(ws + 8 * MB);   // [2048][1024]
  unsigned short* B3T = (unsigned short*)(ws + 12 * MB);   // [1024][2048]
  unsigned short* B4T = (unsigned short*)(ws + 16 * MB);   // [1024][1024]
  float* b1 = (float*)(ws + 18 * MB);
  float* bgf = (float*)(ws + 18 * MB + 8192);
  float* bgb = (float*)(ws + 18 * MB + 16384);
  float* bos = (float*)(ws + 18 * MB + 24576);
  unsigned short* x1b = (unsigned short*)(ws + 19 * MB);   // [16384][2048] bf16
  // region C (64 MB), time-shared: xg -> gates -> g2
  unsigned short* xg = (unsigned short*)(ws + 83 * MB);    // [16384][1024] bf16
  unsigned short* gates = (unsigned short*)(ws + 83 * MB); // [16384][2048] bf16
  unsigned short* g2 = (unsigned short*)(ws + 83 * MB);    // [16384][1024] bf16
  float* Pf = (float*)(ws + 147 * MB);                     // 4 MB
  float* Ee = (float*)(ws + 151 * MB);                     // 4 MB
  float* Ci = (float*)(ws + 155 * MB);                     // 4 MB
  unsigned short* hcat = (unsigned short*)d_out;           // [16384][2048] bf16

  TArgs ta;
  ta.d[0] = {f_Wx, B1T, 1024, 0, 0};
  ta.d[1] = {b_Wx, B1T, 1024, 1024, 0};
  ta.d[2] = {f_Wgx, B2Tf, 1024, 0, 0};
  ta.d[3] = {f_Wga, B2Tf, 1024, 1024, 0};
  ta.d[4] = {b_Wgx, B2Tb, 1024, 0, 0};
  ta.d[5] = {b_Wga, B2Tb, 1024, 1024, 0};
  ta.d[6] = {f_Wo, B3T, 2048, 0, 0};
  ta.d[7] = {b_Wo, B3T, 2048, 0, 1024};
  ta.d[8] = {ld_W, B4T, 1024, 0, 0};

  transpose_pack<<<dim3(9 * 256), dim3(256), 0, stream>>>(ta);
  bias_pack<<<dim3(8), dim3(256), 0, stream>>>(f_bx, b_bx, f_bgx, f_bga, b_bgx,
                                               b_bga, f_bo, b_bo, b1, bgf, bgb,
                                               bos);
  gelu_in<<<dim3(MROWS * HD / 4 / 256), dim3(256), 0, stream>>>(
      (const float4*)x, (ushort4*)xg);

  // G1: x1 = gelu(x) @ [Wx_f | Wx_b] + [bx_f | bx_b]   -> bf16 [16384][2048]
  gemm_bt<EPI_BF16><<<dim3(1024), dim3(512), 0, stream>>>(
      xg, 1024, B1T, 1024, 16, b1, nullptr, nullptr, x1b, 2048);

  // fwd: gate pre-acts (bf16), then 3-phase scan -> hcat[:, 0:1024]
  gemm_bt<EPI_BF16><<<dim3(1024), dim3(512), 0, stream>>>(
      x1b, 2048, B2Tf, 1024, 16, bgf, nullptr, nullptr, gates, 2048);
  scan_p1<0><<<dim3(1, NCHUNK, NBATCH), dim3(256), 0, stream>>>(gates, x1b,
                                                                f_alog, Pf, Ee);
  scan_p2<<<dim3(1, NBATCH), dim3(256), 0, stream>>>(Pf, Ee, Ci);
  scan_p3<0><<<dim3(1, NCHUNK, NBATCH), dim3(256), 0, stream>>>(
      gates, x1b, f_alog, Ci, hcat);

  // bwd: gate pre-acts (reusing gates), reverse scan -> hcat[:, 1024:2048]
  gemm_bt<EPI_BF16><<<dim3(1024), dim3(512), 0, stream>>>(
      x1b + 1024, 2048, B2Tb, 1024, 16, bgb, nullptr, nullptr, gates, 2048);
  scan_p1<1><<<dim3(1, NCHUNK, NBATCH), dim3(256), 0, stream>>>(
      gates, x1b + 1024, b_alog, Pf, Ee);
  scan_p2<<<dim3(1, NBATCH), dim3(256), 0, stream>>>(Pf, Ee, Ci);
  scan_p3<1><<<dim3(1, NCHUNK, NBATCH), dim3(256), 0, stream>>>(
      gates, x1b + 1024, b_alog, Ci, hcat + 1024);

  // G3: g2 = gelu( ([h_f|h_b] @ [Wo_f;Wo_b] + bo_f+bo_b)/2 + x )
  gemm_bt<EPI_X2><<<dim3(512), dim3(512), 0, stream>>>(
      hcat, 2048, B3T, 2048, 8, bos, x, nullptr, g2, 1024);

  // G4: out = g2 @ ld_W + ld_b + x
  gemm_bt<EPI_FINAL><<<dim3(512), dim3(512), 0, stream>>>(
      g2, 1024, B4T, 1024, 8, ld_b, x, out, nullptr, 1024);
}